// Round 1
// 174.114 us; speedup vs baseline: 1.0695x; 1.0695x over previous
//
#include <hip/hip_runtime.h>
#include <hip/hip_bf16.h>

#define B_ 2
#define N_ 2048
#define C_ 1024
#define H_ 16
#define HD_ 64

#define KT 64            // key tile width per flash iteration
#define NT (N_ / KT)     // 32 tiles
#define TILE_E 4096      // elems per staged tile (64x64 bf16 = 8KB)
#define PSTR 72          // P LDS row stride (fallback kernel)
#define NW 8             // waves per block (fallback kernel)
#define QB 128           // q rows per block (fallback kernel)

#define NWM 4            // waves per block (main kernel)
#define QBM 64           // q rows per block (main kernel)

typedef short s16x8 __attribute__((ext_vector_type(8)));
typedef short s16x4 __attribute__((ext_vector_type(4)));
typedef float f32x4 __attribute__((ext_vector_type(4)));

__device__ __forceinline__ ushort f2bf(float x) {
    __hip_bfloat16 h = __float2bfloat16(x);
    return *reinterpret_cast<ushort*>(&h);
}

__device__ __forceinline__ s16x8 cvt8(float4 a, float4 b) {
    union { s16x8 v; __hip_bfloat162 h[4]; } u;
    u.h[0] = __float22bfloat162_rn(float2{a.x, a.y});
    u.h[1] = __float22bfloat162_rn(float2{a.z, a.w});
    u.h[2] = __float22bfloat162_rn(float2{b.x, b.y});
    u.h[3] = __float22bfloat162_rn(float2{b.z, b.w});
    return u.v;
}

// async 16B/lane global -> LDS (DMA, no VGPR round trip)
__device__ __forceinline__ void gll16(const void* g, void* l) {
    __builtin_amdgcn_global_load_lds(
        (const __attribute__((address_space(1))) unsigned*)g,
        (__attribute__((address_space(3))) unsigned*)l, 16, 0, 0);
}

// ---- standalone pack_mask kept for the fallback path only
__global__ __launch_bounds__(256)
void pack_mask(const int* __restrict__ M, unsigned long long* __restrict__ bits) {
    const int gw   = (blockIdx.x * 256 + threadIdx.x) >> 6;
    const int lane = threadIdx.x & 63;
#pragma unroll
    for (int it = 0; it < 16; ++it) {
        const size_t wi = (size_t)gw * 16 + it;
        unsigned long long bal = __ballot(M[wi * 64 + lane] != 0);
        if (lane == 0) bits[wi] = bal;
    }
}

// ---- fused prepass: pack_mask (blocks 0..2047), conv_k (2048..4095),
//      conv_v (4096..4607). One launch instead of three.
__global__ __launch_bounds__(256)
void prepass(const int* __restrict__ M, const float* __restrict__ K,
             const float* __restrict__ V, unsigned long long* __restrict__ bits,
             ushort* __restrict__ Kw, ushort* __restrict__ Vw) {
    const int bid = blockIdx.x;
    const int tid = threadIdx.x;
    if (bid < 2048) {
        // bit-pack mask. 8192 waves x 16 independent words.
        const int gw   = (bid * 256 + tid) >> 6;
        const int lane = tid & 63;
#pragma unroll
        for (int it = 0; it < 16; ++it) {
            const size_t wi = (size_t)gw * 16 + it;
            unsigned long long bal = __ballot(M[wi * 64 + lane] != 0);
            if (lane == 0) bits[wi] = bal;
        }
    } else if (bid < 4096) {
        // K fp32 -> bf16, tile-major with d-block XOR swizzle baked in.
        const int gt = (bid - 2048) * 256 + tid;
        const int b  = gt >> 18;
        const int h  = (gt >> 14) & 15;
        const int n  = (gt >> 3) & 2047;
        const int db = gt & 7;
        const size_t src = (size_t)(b * N_ + n) * C_ + h * 64 + db * 8;
        float4 f0 = *(const float4*)(K + src);
        float4 f1 = *(const float4*)(K + src + 4);
        const int key = n & 63, kt = n >> 6;
        ushort* dst = Kw + (size_t)((b * H_ + h) * NT + kt) * TILE_E
                         + key * 64 + ((db ^ (key & 7)) * 8);
        *(s16x8*)dst = cvt8(f0, f1);
    } else {
        // V fp32 -> bf16 TRANSPOSED, tile-major, key-block XOR swizzle.
        const int gt  = (bid - 4096) * 256 + tid;
        const int b   = gt >> 16;
        const int h   = (gt >> 12) & 15;
        const int kt  = (gt >> 7) & 31;
        const int kb4 = (gt >> 3) & 15;
        const int db  = gt & 7;
        const int key0 = kb4 * 4;
        float f[4][8];
#pragma unroll
        for (int i = 0; i < 4; ++i) {
            const size_t src = (size_t)(b * N_ + kt * 64 + key0 + i) * C_ + h * 64 + db * 8;
            *(float4*)&f[i][0] = *(const float4*)(V + src);
            *(float4*)&f[i][4] = *(const float4*)(V + src + 4);
        }
        ushort* tb = Vw + (size_t)((b * H_ + h) * NT + kt) * TILE_E;
#pragma unroll
        for (int j = 0; j < 8; ++j) {
            const int d = db * 8 + j;
            union { s16x4 v; __hip_bfloat162 h2[2]; } u;
            u.h2[0] = __float22bfloat162_rn(float2{f[0][j], f[1][j]});
            u.h2[1] = __float22bfloat162_rn(float2{f[2][j], f[3][j]});
            *(s16x4*)(tb + d * 64 + (((key0 >> 3) ^ (d & 7)) * 8) + (key0 & 7)) = u.v;
        }
    }
}

// ---- main: 256-thread blocks, 4 blocks/CU (LDS=40960B exactly), XCD-swizzled
__global__ __launch_bounds__(256, 4)
void mha_fwd(const float* __restrict__ Q, const ushort* __restrict__ Kw,
             const ushort* __restrict__ Vw, const unsigned* __restrict__ bits,
             float* __restrict__ O) {
    __shared__ ushort Kl[2][TILE_E];       // 16 KB
    __shared__ ushort Vt[2][TILE_E];       // 16 KB
    __shared__ ushort Pl[NWM][16 * 64];    //  8 KB (stride 64, XOR slot swizzle)

    // XCD-aware bijective decode: xcd = sid&7 owns heads 4*xcd..4*xcd+3,
    // so each XCD's L2 holds 4 heads x 512KB K/V = 2MB (fits 4MB).
    const int sid = blockIdx.x;
    const int jj  = sid >> 3;
    const int hb  = ((sid & 7) << 2) | (jj & 3);   // 0..31 = b*16+h
    const int qt  = jj >> 2;                        // 0..31
    const int h   = hb & 15;
    const int b   = hb >> 4;

    const int tid  = threadIdx.x;
    const int w    = tid >> 6;
    const int lane = tid & 63;
    const int l16  = lane & 15;
    const int quad = lane >> 4;

    const size_t head_off = (size_t)b * N_ * C_ + (size_t)h * HD_;
    const int qb = qt * QBM + w * 16;

    // Q fragment (B-operand of S^T = K Q^T); fold 1/8*log2(e): log2-domain scores
    const float qs = 0.125f * 1.44269504088896f;
    const size_t qoff = head_off + (size_t)(qb + l16) * C_ + quad * 8;
    float4 q0 = *(const float4*)(Q + qoff);
    float4 q1 = *(const float4*)(Q + qoff + 4);
    float4 q2 = *(const float4*)(Q + qoff + 32);
    float4 q3 = *(const float4*)(Q + qoff + 36);
    q0.x*=qs; q0.y*=qs; q0.z*=qs; q0.w*=qs;
    q1.x*=qs; q1.y*=qs; q1.z*=qs; q1.w*=qs;
    q2.x*=qs; q2.y*=qs; q2.z*=qs; q2.w*=qs;
    q3.x*=qs; q3.y*=qs; q3.z*=qs; q3.w*=qs;
    const s16x8 qa0 = cvt8(q0, q1);
    const s16x8 qa1 = cvt8(q2, q3);

    f32x4 acc[4];
#pragma unroll
    for (int c = 0; c < 4; ++c) acc[c] = f32x4{0.f, 0.f, 0.f, 0.f};
    float2 ls2 = {0.f, 0.f};          // packed partial row-sums

    // hoisted fragment element bases (loop-invariant)
    const int fbase = l16 * 64 + ((quad ^ (l16 & 7)) * 8);
    const int prow  = l16 * 64;            // P row base (ushorts)
    const int pswz  = (l16 & 7) << 1;      // XOR on 8B-slot index (even -> keeps
                                           // 16B read pairs adjacent & aligned)

    // staging pointers: 256 threads cover an 8KB tile in 2 rounds of 16B/lane
    const size_t tilebase = (size_t)((b * H_ + h) * NT) * TILE_E;
    const ushort* Kg = Kw + tilebase + (size_t)tid * 8;
    const ushort* Vg = Vw + tilebase + (size_t)tid * 8;

    const unsigned* mq = bits + ((size_t)b * N_ + qb + l16) * (N_ / 32);

    // issue tile 0 into buffer 0 (drained by first barrier)
    gll16(Kg,        &Kl[0][w * 512]);
    gll16(Kg + 2048, &Kl[0][w * 512 + 2048]);
    gll16(Vg,        &Vt[0][w * 512]);
    gll16(Vg + 2048, &Vt[0][w * 512 + 2048]);
    const ushort* Kg_pf = Kg + TILE_E;
    const ushort* Vg_pf = Vg + TILE_E;

    uint4 mw = *(const uint4*)mq;  mq += 4;   // mask words for first tile pair

    for (int kt2 = 0; kt2 < NT; kt2 += 2) {
        // prefetch next pair's mask words (reads <=16B past bits land in Kw
        // region of the workspace on the final iteration -- allocated, unused)
        const uint4 mw_nxt = *(const uint4*)mq;  mq += 4;
        const bool pf1 = (kt2 + 2 < NT);
#pragma unroll
        for (int u = 0; u < 2; ++u) {        // u == buffer index (compile-time)
            __syncthreads();   // tile staged; all waves done reading other buf
            if (u == 0 || pf1) {             // prefetch next tile into other buf
                gll16(Kg_pf,        &Kl[1 - u][w * 512]);
                gll16(Kg_pf + 2048, &Kl[1 - u][w * 512 + 2048]);
                gll16(Vg_pf,        &Vt[1 - u][w * 512]);
                gll16(Vg_pf + 2048, &Vt[1 - u][w * 512 + 2048]);
                Kg_pf += TILE_E;  Vg_pf += TILE_E;
            }
            const unsigned w0 = u ? mw.z : mw.x;
            const unsigned w1 = u ? mw.w : mw.y;

            // S^T = K Q^T : 64 keys x 16 q (row=key, col=qrow), log2-domain
            f32x4 s[4];
            __builtin_amdgcn_s_setprio(1);
#pragma unroll
            for (int t = 0; t < 4; ++t) {
                s16x8 kb0 = *(const s16x8*)(&Kl[u][fbase + t * 1024]);
                s16x8 kb1 = *(const s16x8*)(&Kl[u][(fbase ^ 32) + t * 1024]);
                f32x4 z = {0.f, 0.f, 0.f, 0.f};
                z = __builtin_amdgcn_mfma_f32_16x16x32_bf16(kb0, qa0, z, 0, 0, 0);
                z = __builtin_amdgcn_mfma_f32_16x16x32_bf16(kb1, qa1, z, 0, 0, 0);
                s[t] = z;
            }
            __builtin_amdgcn_s_setprio(0);

            // softmax, unnormalized: p = exp2(s); common scale cancels in O
            const unsigned a0 = w0 >> (quad * 4);
            const unsigned a1 = w1 >> (quad * 4);
#pragma unroll
            for (int t = 0; t < 4; ++t) {
                const unsigned aw = (t < 2) ? a0 : a1;
                const int sh = (t & 1) * 16;
                float p0 = __builtin_amdgcn_exp2f(((aw >> (sh + 0)) & 1u) ? s[t][0] : -1e9f);
                float p1 = __builtin_amdgcn_exp2f(((aw >> (sh + 1)) & 1u) ? s[t][1] : -1e9f);
                float p2 = __builtin_amdgcn_exp2f(((aw >> (sh + 2)) & 1u) ? s[t][2] : -1e9f);
                float p3 = __builtin_amdgcn_exp2f(((aw >> (sh + 3)) & 1u) ? s[t][3] : -1e9f);
                ls2.x += p0 + p2;
                ls2.y += p1 + p3;
                union { s16x4 v; __hip_bfloat162 h2[2]; } uu;
                uu.h2[0] = __float22bfloat162_rn(float2{p0, p1});
                uu.h2[1] = __float22bfloat162_rn(float2{p2, p3});
                // write slot S = t*4+quad, XOR-swizzled by row (bank-floor)
                *(s16x4*)(&Pl[w][prow + ((((t << 2) | quad) ^ pswz) << 2)]) = uu.v;
            }
            // per-wave LDS write->read: compiler lgkmcnt, no barrier needed

            // PV: A = P (16 q x 64 keys), B = Vt (baked swizzle)
            __builtin_amdgcn_s_setprio(1);
#pragma unroll
            for (int half = 0; half < 2; ++half) {
                // read slots (half*8+quad*2, +1), same XOR (even -> pair stays
                // adjacent and 16B-aligned)
                s16x8 pa = *(const s16x8*)(
                    &Pl[w][prow + ((((half << 3) | (quad << 1)) ^ pswz) << 2)]);
#pragma unroll
                for (int c = 0; c < 4; ++c) {
                    const int vidx = (half ? (fbase ^ 32) : fbase) + c * 1024;
                    s16x8 vb = *(const s16x8*)(&Vt[u][vidx]);
                    acc[c] = __builtin_amdgcn_mfma_f32_16x16x32_bf16(pa, vb, acc[c], 0, 0, 0);
                }
            }
            __builtin_amdgcn_s_setprio(0);
        }
        mw = mw_nxt;
    }

    float lsum = ls2.x + ls2.y;
    lsum += __shfl_xor(lsum, 16);
    lsum += __shfl_xor(lsum, 32);

#pragma unroll
    for (int r = 0; r < 4; ++r) {
        const float inv = 1.0f / __shfl(lsum, quad * 4 + r);
        const size_t obase = head_off + (size_t)(qb + quad * 4 + r) * C_;
        O[obase + l16]      = acc[0][r] * inv;
        O[obase + l16 + 16] = acc[1][r] * inv;
        O[obase + l16 + 32] = acc[2][r] * inv;
        O[obase + l16 + 48] = acc[3][r] * inv;
    }
}

// ================== fallback (R6 verbatim): used if ws_size too small =========
#define KSTR 72
#define VSTR 72
__global__ __launch_bounds__(512, 4)
void mha_fwd_fb(const float* __restrict__ Q, const float* __restrict__ K,
                const float* __restrict__ V, const unsigned* __restrict__ bits,
                float* __restrict__ O) {
    __shared__ ushort Kl[2][KT * KSTR];
    __shared__ ushort Vt[2][HD_ * VSTR];
    __shared__ ushort Pl[NW][16 * PSTR];
    const int qt = blockIdx.x, h = blockIdx.y, b = blockIdx.z, tid = threadIdx.x;
    const int w = tid >> 6, lane = tid & 63, l16 = lane & 15, quad = lane >> 4;
    const size_t head_off = (size_t)b * N_ * C_ + (size_t)h * HD_;
    const int qb = qt * QB + w * 16;
    const float qs = 0.125f * 1.44269504088896f;
    const size_t qoff = head_off + (size_t)(qb + l16) * C_ + quad * 8;
    float4 q0 = *(const float4*)(Q + qoff);
    float4 q1 = *(const float4*)(Q + qoff + 4);
    float4 q2 = *(const float4*)(Q + qoff + 32);
    float4 q3 = *(const float4*)(Q + qoff + 36);
    q0.x*=qs; q0.y*=qs; q0.z*=qs; q0.w*=qs;
    q1.x*=qs; q1.y*=qs; q1.z*=qs; q1.w*=qs;
    q2.x*=qs; q2.y*=qs; q2.z*=qs; q2.w*=qs;
    q3.x*=qs; q3.y*=qs; q3.z*=qs; q3.w*=qs;
    const s16x8 qa0 = cvt8(q0, q1);
    const s16x8 qa1 = cvt8(q2, q3);
    f32x4 acc[4];
#pragma unroll
    for (int c = 0; c < 4; ++c) acc[c] = f32x4{0.f, 0.f, 0.f, 0.f};
    float lsum = 0.f;
    const int skey = tid >> 3, sd0 = (tid & 7) * 8;
    const int kp = tid >> 4, vd0 = (tid & 15) * 4;
    const int vcol = 2 * (kp & 3) + ((((kp >> 2) ^ (vd0 >> 3)) & 7) << 3);
    const unsigned* brow = bits + ((size_t)b * N_ + qb + l16) * (N_ / 32);
    const float SHIFT = 16.0f;
    {
        const size_t kbase = head_off + (size_t)skey * C_ + sd0;
        float4 kA = *(const float4*)(K + kbase);
        float4 kB = *(const float4*)(K + kbase + 4);
        *(s16x8*)(&Kl[0][skey * KSTR + sd0]) = cvt8(kA, kB);
        const size_t vbase = head_off + (size_t)(2 * kp) * C_ + vd0;
        float4 vA = *(const float4*)(V + vbase);
        float4 vB = *(const float4*)(V + vbase + C_);
        const float* ap = (const float*)&vA;
        const float* bp = (const float*)&vB;
#pragma unroll
        for (int i = 0; i < 4; ++i) {
            __hip_bfloat162 pr = __float22bfloat162_rn(float2{ap[i], bp[i]});
            *(unsigned*)(&Vt[0][(vd0 + i) * VSTR + vcol]) = *(unsigned*)&pr;
        }
    }
    for (int kt = 0; kt < NT; ++kt) {
        const int cur = kt & 1;
        float4 kA, kB, vA, vB;
        const bool has_next = (kt + 1 < NT);
        if (has_next) {
            const size_t kbase = head_off + (size_t)((kt + 1) * KT + skey) * C_ + sd0;
            kA = *(const float4*)(K + kbase);
            kB = *(const float4*)(K + kbase + 4);
            const size_t vbase = head_off + (size_t)((kt + 1) * KT + 2 * kp) * C_ + vd0;
            vA = *(const float4*)(V + vbase);
            vB = *(const float4*)(V + vbase + C_);
        }
        const unsigned w0 = brow[2 * kt];
        const unsigned w1 = brow[2 * kt + 1];
        __syncthreads();
        f32x4 s[4];
#pragma unroll
        for (int t = 0; t < 4; ++t) {
            s16x8 kb0 = *(const s16x8*)(&Kl[cur][(t * 16 + l16) * KSTR + quad * 8]);
            s16x8 kb1 = *(const s16x8*)(&Kl[cur][(t * 16 + l16) * KSTR + quad * 8 + 32]);
            f32x4 z = {0.f, 0.f, 0.f, 0.f};
            z = __builtin_amdgcn_mfma_f32_16x16x32_bf16(kb0, qa0, z, 0, 0, 0);
            z = __builtin_amdgcn_mfma_f32_16x16x32_bf16(kb1, qa1, z, 0, 0, 0);
            s[t] = z;
        }
        const unsigned a0 = w0 >> (quad * 4);
        const unsigned a1 = w1 >> (quad * 4);
#pragma unroll
        for (int t = 0; t < 4; ++t) {
            const unsigned aw = (t < 2) ? a0 : a1;
            const int sh = (t & 1) * 16;
            float p0 = exp2f((((aw >> (sh + 0)) & 1u) ? s[t][0] : -1e9f) - SHIFT);
            float p1 = exp2f((((aw >> (sh + 1)) & 1u) ? s[t][1] : -1e9f) - SHIFT);
            float p2 = exp2f((((aw >> (sh + 2)) & 1u) ? s[t][2] : -1e9f) - SHIFT);
            float p3 = exp2f((((aw >> (sh + 3)) & 1u) ? s[t][3] : -1e9f) - SHIFT);
            lsum += (p0 + p1) + (p2 + p3);
            union { s16x4 v; __hip_bfloat162 h2[2]; } uu;
            uu.h2[0] = __float22bfloat162_rn(float2{p0, p1});
            uu.h2[1] = __float22bfloat162_rn(float2{p2, p3});
            *(s16x4*)(&Pl[w][l16 * PSTR + t * 16 + quad * 4]) = uu.v;
        }
#pragma unroll
        for (int half = 0; half < 2; ++half) {
            s16x8 pa = *(const s16x8*)(&Pl[w][l16 * PSTR + half * 32 + quad * 8]);
#pragma unroll
            for (int c = 0; c < 4; ++c) {
                const int dr = c * 16 + l16;
                const int blk = (half * 4 + quad) ^ ((dr >> 3) & 7);
                s16x8 vb = *(const s16x8*)(&Vt[cur][dr * VSTR + blk * 8]);
                acc[c] = __builtin_amdgcn_mfma_f32_16x16x32_bf16(pa, vb, acc[c], 0, 0, 0);
            }
        }
        if (has_next) {
            *(s16x8*)(&Kl[1 - cur][skey * KSTR + sd0]) = cvt8(kA, kB);
            const float* ap = (const float*)&vA;
            const float* bp = (const float*)&vB;
#pragma unroll
            for (int i = 0; i < 4; ++i) {
                __hip_bfloat162 pr = __float22bfloat162_rn(float2{ap[i], bp[i]});
                *(unsigned*)(&Vt[1 - cur][(vd0 + i) * VSTR + vcol]) = *(unsigned*)&pr;
            }
        }
    }
    lsum += __shfl_xor(lsum, 16);
    lsum += __shfl_xor(lsum, 32);
#pragma unroll
    for (int r = 0; r < 4; ++r) {
        const float inv = 1.0f / __shfl(lsum, quad * 4 + r);
        const size_t obase = head_off + (size_t)(qb + quad * 4 + r) * C_;
        O[obase + l16]      = acc[0][r] * inv;
        O[obase + l16 + 16] = acc[1][r] * inv;
        O[obase + l16 + 32] = acc[2][r] * inv;
        O[obase + l16 + 48] = acc[3][r] * inv;
    }
}

extern "C" void kernel_launch(void* const* d_in, const int* in_sizes, int n_in,
                              void* d_out, int out_size, void* d_ws, size_t ws_size,
                              hipStream_t stream) {
    const float* q = (const float*)d_in[0];
    const float* k = (const float*)d_in[1];
    const float* v = (const float*)d_in[2];
    const int*   m = (const int*)d_in[3];
    float*       o = (float*)d_out;

    const size_t BITS_BYTES = (size_t)B_ * N_ * N_ / 8;          // 1 MiB
    const size_t KV_BYTES   = (size_t)B_ * H_ * N_ * HD_ * 2;    // 8.39 MB each
    const size_t NEED       = BITS_BYTES + 2 * KV_BYTES;

    unsigned long long* bits = (unsigned long long*)d_ws;

    if (ws_size >= NEED) {
        ushort* kw = (ushort*)((char*)d_ws + BITS_BYTES);
        ushort* vw = (ushort*)((char*)d_ws + BITS_BYTES + KV_BYTES);
        hipLaunchKernelGGL(prepass, dim3(4608), dim3(256), 0, stream,
                           m, k, v, bits, kw, vw);
        hipLaunchKernelGGL(mha_fwd, dim3(1024), dim3(256), 0, stream,
                           q, kw, vw, (const unsigned*)bits, o);
    } else {
        hipLaunchKernelGGL(pack_mask, dim3(2048), dim3(256), 0, stream, m, bits);
        dim3 grid(N_ / QB, H_, B_);
        hipLaunchKernelGGL(mha_fwd_fb, grid, dim3(512), 0, stream,
                           q, k, v, (const unsigned*)bits, o);
    }
}

// Round 3
// 173.794 us; speedup vs baseline: 1.0715x; 1.0018x over previous
//
#include <hip/hip_runtime.h>
#include <hip/hip_bf16.h>

#define B_ 2
#define N_ 2048
#define C_ 1024
#define H_ 16
#define HD_ 64

#define KT 64            // key tile width per flash iteration
#define NT (N_ / KT)     // 32 tiles
#define TILE_E 4096      // elems per staged tile (64x64 bf16 = 8KB)
#define PSTR 72          // P LDS row stride (fallback kernel)
#define NW 8             // waves per block (fallback kernel)
#define QB 128           // q rows per block (fallback kernel)

#define NWM 2            // waves per block (main kernel)
#define QBM 64           // q rows per block (main: 32 per wave)

typedef short s16x8 __attribute__((ext_vector_type(8)));
typedef short s16x4 __attribute__((ext_vector_type(4)));
typedef float f32x4 __attribute__((ext_vector_type(4)));

__device__ __forceinline__ s16x8 cvt8(float4 a, float4 b) {
    union { s16x8 v; __hip_bfloat162 h[4]; } u;
    u.h[0] = __float22bfloat162_rn(float2{a.x, a.y});
    u.h[1] = __float22bfloat162_rn(float2{a.z, a.w});
    u.h[2] = __float22bfloat162_rn(float2{b.x, b.y});
    u.h[3] = __float22bfloat162_rn(float2{b.z, b.w});
    return u.v;
}

// async 16B/lane global -> LDS (DMA, no VGPR round trip)
__device__ __forceinline__ void gll16(const void* g, void* l) {
    __builtin_amdgcn_global_load_lds(
        (const __attribute__((address_space(1))) unsigned*)g,
        (__attribute__((address_space(3))) unsigned*)l, 16, 0, 0);
}

// ---- standalone pack_mask kept for the fallback path only
__global__ __launch_bounds__(256)
void pack_mask(const int* __restrict__ M, unsigned long long* __restrict__ bits) {
    const int gw   = (blockIdx.x * 256 + threadIdx.x) >> 6;
    const int lane = threadIdx.x & 63;
#pragma unroll
    for (int it = 0; it < 16; ++it) {
        const size_t wi = (size_t)gw * 16 + it;
        unsigned long long bal = __ballot(M[wi * 64 + lane] != 0);
        if (lane == 0) bits[wi] = bal;
    }
}

// ---- fused prepass: mask pack (blocks 0..2047), conv_k (2048..4095),
//      conv_v (4096..4607).
__global__ __launch_bounds__(256)
void prepass(const int* __restrict__ M, const float* __restrict__ K,
             const float* __restrict__ V, unsigned long long* __restrict__ bits,
             ushort* __restrict__ Kw, ushort* __restrict__ Vw) {
    const int bid = blockIdx.x;
    const int tid = threadIdx.x;
    if (bid < 2048) {
        // vectorized mask pack: 16 ints/thread (4x int4 = 64B), 1 ushort out.
        // bit j of thread gt's ushort = M[gt*16+j]; ushort store at byte gt*2
        // reproduces the exact little-endian 64-bit word layout.
        const int gt = bid * 256 + tid;            // 0..524287
        const int4* src = (const int4*)M + (size_t)gt * 4;
        unsigned r = 0;
#pragma unroll
        for (int c = 0; c < 4; ++c) {
            const int4 m4 = src[c];
            r |= (m4.x != 0 ? 1u : 0u) << (c * 4 + 0);
            r |= (m4.y != 0 ? 1u : 0u) << (c * 4 + 1);
            r |= (m4.z != 0 ? 1u : 0u) << (c * 4 + 2);
            r |= (m4.w != 0 ? 1u : 0u) << (c * 4 + 3);
        }
        ((ushort*)bits)[gt] = (ushort)r;
    } else if (bid < 4096) {
        // K fp32 -> bf16, tile-major with d-block XOR swizzle baked in.
        const int gt = (bid - 2048) * 256 + tid;
        const int b  = gt >> 18;
        const int h  = (gt >> 14) & 15;
        const int n  = (gt >> 3) & 2047;
        const int db = gt & 7;
        const size_t src = (size_t)(b * N_ + n) * C_ + h * 64 + db * 8;
        float4 f0 = *(const float4*)(K + src);
        float4 f1 = *(const float4*)(K + src + 4);
        const int key = n & 63, kt = n >> 6;
        ushort* dst = Kw + (size_t)((b * H_ + h) * NT + kt) * TILE_E
                         + key * 64 + ((db ^ (key & 7)) * 8);
        *(s16x8*)dst = cvt8(f0, f1);
    } else {
        // V fp32 -> bf16 TRANSPOSED, tile-major, key-block XOR swizzle.
        const int gt  = (bid - 4096) * 256 + tid;
        const int b   = gt >> 16;
        const int h   = (gt >> 12) & 15;
        const int kt  = (gt >> 7) & 31;
        const int kb4 = (gt >> 3) & 15;
        const int db  = gt & 7;
        const int key0 = kb4 * 4;
        float f[4][8];
#pragma unroll
        for (int i = 0; i < 4; ++i) {
            const size_t src = (size_t)(b * N_ + kt * 64 + key0 + i) * C_ + h * 64 + db * 8;
            *(float4*)&f[i][0] = *(const float4*)(V + src);
            *(float4*)&f[i][4] = *(const float4*)(V + src + 4);
        }
        ushort* tb = Vw + (size_t)((b * H_ + h) * NT + kt) * TILE_E;
#pragma unroll
        for (int j = 0; j < 8; ++j) {
            const int d = db * 8 + j;
            union { s16x4 v; __hip_bfloat162 h2[2]; } u;
            u.h2[0] = __float22bfloat162_rn(float2{f[0][j], f[1][j]});
            u.h2[1] = __float22bfloat162_rn(float2{f[2][j], f[3][j]});
            *(s16x4*)(tb + d * 64 + (((key0 >> 3) ^ (d & 7)) * 8) + (key0 & 7)) = u.v;
        }
    }
}

// ---- main: 128-thread blocks, 32 q-rows/wave, 4 blocks/CU (LDS=40960B exactly)
__global__ __launch_bounds__(128, 2)
void mha_fwd(const float* __restrict__ Q, const ushort* __restrict__ Kw,
             const ushort* __restrict__ Vw, const unsigned* __restrict__ bits,
             float* __restrict__ O) {
    __shared__ ushort Kl[2][TILE_E];         // 16 KB
    __shared__ ushort Vt[2][TILE_E];         // 16 KB
    __shared__ ushort Pl[NWM][2][16 * 64];   //  8 KB (per wave x per q-set)

    // XCD-aware bijective decode: xcd = sid&7 owns heads 4*xcd..4*xcd+3
    const int sid = blockIdx.x;
    const int jj  = sid >> 3;                  // 0..127
    const int hb  = ((sid & 7) << 2) | (jj & 3);
    const int qt  = jj >> 2;                   // 0..31
    const int h   = hb & 15;
    const int b   = hb >> 4;

    const int tid  = threadIdx.x;              // 0..127
    const int w    = tid >> 6;                 // 0..1
    const int lane = tid & 63;
    const int l16  = lane & 15;
    const int quad = lane >> 4;

    const size_t head_off = (size_t)b * N_ * C_ + (size_t)h * HD_;
    const int qb = qt * QBM + w * 32;          // wave's first q row

    // Q fragments for both 16-row sets; fold 1/8*log2(e): log2-domain scores
    const float qs = 0.125f * 1.44269504088896f;
    const size_t qoffA = head_off + (size_t)(qb + l16) * C_ + quad * 8;
    const size_t qoffB = head_off + (size_t)(qb + 16 + l16) * C_ + quad * 8;
    float4 q0 = *(const float4*)(Q + qoffA);
    float4 q1 = *(const float4*)(Q + qoffA + 4);
    float4 q2 = *(const float4*)(Q + qoffA + 32);
    float4 q3 = *(const float4*)(Q + qoffA + 36);
    float4 q4 = *(const float4*)(Q + qoffB);
    float4 q5 = *(const float4*)(Q + qoffB + 4);
    float4 q6 = *(const float4*)(Q + qoffB + 32);
    float4 q7 = *(const float4*)(Q + qoffB + 36);
    q0.x*=qs; q0.y*=qs; q0.z*=qs; q0.w*=qs;
    q1.x*=qs; q1.y*=qs; q1.z*=qs; q1.w*=qs;
    q2.x*=qs; q2.y*=qs; q2.z*=qs; q2.w*=qs;
    q3.x*=qs; q3.y*=qs; q3.z*=qs; q3.w*=qs;
    q4.x*=qs; q4.y*=qs; q4.z*=qs; q4.w*=qs;
    q5.x*=qs; q5.y*=qs; q5.z*=qs; q5.w*=qs;
    q6.x*=qs; q6.y*=qs; q6.z*=qs; q6.w*=qs;
    q7.x*=qs; q7.y*=qs; q7.z*=qs; q7.w*=qs;
    const s16x8 qa0 = cvt8(q0, q1);
    const s16x8 qa1 = cvt8(q2, q3);
    const s16x8 qa2 = cvt8(q4, q5);
    const s16x8 qa3 = cvt8(q6, q7);

    // constant all-ones bf16 B-fragment: row-sum via MFMA (ones-trick)
    s16x8 onesb;
#pragma unroll
    for (int i = 0; i < 8; ++i) onesb[i] = (short)0x3F80;

    f32x4 accA[4], accB[4], sumA, sumB;
#pragma unroll
    for (int c = 0; c < 4; ++c) { accA[c] = f32x4{0,0,0,0}; accB[c] = f32x4{0,0,0,0}; }
    sumA = f32x4{0,0,0,0};  sumB = f32x4{0,0,0,0};

    // hoisted fragment element bases (loop-invariant)
    const int fbase = l16 * 64 + ((quad ^ (l16 & 7)) * 8);
    const int prow  = l16 * 64;            // P row base (ushorts)
    const int pswz  = (l16 & 7) << 1;      // XOR on 8B-slot index (even)

    // staging: 128 threads cover an 8KB tile in 4 rounds of 16B/lane
    const size_t tilebase = (size_t)((b * H_ + h) * NT) * TILE_E;
    const ushort* Kg = Kw + tilebase + (size_t)tid * 8;
    const ushort* Vg = Vw + tilebase + (size_t)tid * 8;

    const unsigned* mqA = bits + ((size_t)b * N_ + qb + l16) * (N_ / 32);
    const unsigned* mqB = mqA + 16 * (N_ / 32);

    // issue tile 0 into buffer 0 (drained by first barrier)
#pragma unroll
    for (int c = 0; c < 4; ++c) {
        gll16(Kg + c * 1024, &Kl[0][w * 512 + c * 1024]);
        gll16(Vg + c * 1024, &Vt[0][w * 512 + c * 1024]);
    }
    const ushort* Kg_pf = Kg + TILE_E;
    const ushort* Vg_pf = Vg + TILE_E;

    uint4 mwA = *(const uint4*)mqA;  mqA += 4;
    uint4 mwB = *(const uint4*)mqB;  mqB += 4;

    for (int kt2 = 0; kt2 < NT; kt2 += 2) {
        // prefetch next pair's mask words (final over-read lands in Kw region)
        const uint4 mwA_n = *(const uint4*)mqA;  mqA += 4;
        const uint4 mwB_n = *(const uint4*)mqB;  mqB += 4;
        const bool pf1 = (kt2 + 2 < NT);
#pragma unroll
        for (int u = 0; u < 2; ++u) {        // u == buffer index (compile-time)
            __syncthreads();   // tile staged; all waves done reading other buf
            if (u == 0 || pf1) {             // prefetch next tile into other buf
#pragma unroll
                for (int c = 0; c < 4; ++c) {
                    gll16(Kg_pf + c * 1024, &Kl[1 - u][w * 512 + c * 1024]);
                    gll16(Vg_pf + c * 1024, &Vt[1 - u][w * 512 + c * 1024]);
                }
                Kg_pf += TILE_E;  Vg_pf += TILE_E;
            }
            const unsigned wA0 = u ? mwA.z : mwA.x;
            const unsigned wA1 = u ? mwA.w : mwA.y;
            const unsigned wB0 = u ? mwB.z : mwB.x;
            const unsigned wB1 = u ? mwB.w : mwB.y;

            // S^T = K Q^T : 64 keys x 32 q, log2-domain; K-frags shared by sets
            f32x4 sA[4], sB[4];
            __builtin_amdgcn_s_setprio(1);
#pragma unroll
            for (int t = 0; t < 4; ++t) {
                s16x8 kb0 = *(const s16x8*)(&Kl[u][fbase + t * 1024]);
                s16x8 kb1 = *(const s16x8*)(&Kl[u][(fbase ^ 32) + t * 1024]);
                f32x4 zA = {0.f,0.f,0.f,0.f}, zB = {0.f,0.f,0.f,0.f};
                zA = __builtin_amdgcn_mfma_f32_16x16x32_bf16(kb0, qa0, zA, 0, 0, 0);
                zA = __builtin_amdgcn_mfma_f32_16x16x32_bf16(kb1, qa1, zA, 0, 0, 0);
                zB = __builtin_amdgcn_mfma_f32_16x16x32_bf16(kb0, qa2, zB, 0, 0, 0);
                zB = __builtin_amdgcn_mfma_f32_16x16x32_bf16(kb1, qa3, zB, 0, 0, 0);
                sA[t] = zA;  sB[t] = zB;
            }
            __builtin_amdgcn_s_setprio(0);

            // softmax (unnormalized p = exp2(s)); row-sums come from MFMA later
            const unsigned aA0 = wA0 >> (quad * 4);
            const unsigned aA1 = wA1 >> (quad * 4);
#pragma unroll
            for (int t = 0; t < 4; ++t) {
                const unsigned aw = (t < 2) ? aA0 : aA1;
                const int sh = (t & 1) * 16;
                float p0 = __builtin_amdgcn_exp2f(((aw >> (sh + 0)) & 1u) ? sA[t][0] : -1e9f);
                float p1 = __builtin_amdgcn_exp2f(((aw >> (sh + 1)) & 1u) ? sA[t][1] : -1e9f);
                float p2 = __builtin_amdgcn_exp2f(((aw >> (sh + 2)) & 1u) ? sA[t][2] : -1e9f);
                float p3 = __builtin_amdgcn_exp2f(((aw >> (sh + 3)) & 1u) ? sA[t][3] : -1e9f);
                union { s16x4 v; __hip_bfloat162 h2[2]; } uu;
                uu.h2[0] = __float22bfloat162_rn(float2{p0, p1});
                uu.h2[1] = __float22bfloat162_rn(float2{p2, p3});
                *(s16x4*)(&Pl[w][0][prow + ((((t << 2) | quad) ^ pswz) << 2)]) = uu.v;
            }
            const unsigned aB0 = wB0 >> (quad * 4);
            const unsigned aB1 = wB1 >> (quad * 4);
#pragma unroll
            for (int t = 0; t < 4; ++t) {
                const unsigned aw = (t < 2) ? aB0 : aB1;
                const int sh = (t & 1) * 16;
                float p0 = __builtin_amdgcn_exp2f(((aw >> (sh + 0)) & 1u) ? sB[t][0] : -1e9f);
                float p1 = __builtin_amdgcn_exp2f(((aw >> (sh + 1)) & 1u) ? sB[t][1] : -1e9f);
                float p2 = __builtin_amdgcn_exp2f(((aw >> (sh + 2)) & 1u) ? sB[t][2] : -1e9f);
                float p3 = __builtin_amdgcn_exp2f(((aw >> (sh + 3)) & 1u) ? sB[t][3] : -1e9f);
                union { s16x4 v; __hip_bfloat162 h2[2]; } uu;
                uu.h2[0] = __float22bfloat162_rn(float2{p0, p1});
                uu.h2[1] = __float22bfloat162_rn(float2{p2, p3});
                *(s16x4*)(&Pl[w][1][prow + ((((t << 2) | quad) ^ pswz) << 2)]) = uu.v;
            }

            // PV + ones-sum, set A then set B (B's P writes already in flight)
            __builtin_amdgcn_s_setprio(1);
#pragma unroll
            for (int half = 0; half < 2; ++half) {
                s16x8 pa = *(const s16x8*)(
                    &Pl[w][0][prow + ((((half << 3) | (quad << 1)) ^ pswz) << 2)]);
#pragma unroll
                for (int c = 0; c < 4; ++c) {
                    const int vidx = (half ? (fbase ^ 32) : fbase) + c * 1024;
                    s16x8 vb = *(const s16x8*)(&Vt[u][vidx]);
                    accA[c] = __builtin_amdgcn_mfma_f32_16x16x32_bf16(pa, vb, accA[c], 0, 0, 0);
                }
                sumA = __builtin_amdgcn_mfma_f32_16x16x32_bf16(pa, onesb, sumA, 0, 0, 0);
            }
#pragma unroll
            for (int half = 0; half < 2; ++half) {
                s16x8 pa = *(const s16x8*)(
                    &Pl[w][1][prow + ((((half << 3) | (quad << 1)) ^ pswz) << 2)]);
#pragma unroll
                for (int c = 0; c < 4; ++c) {
                    const int vidx = (half ? (fbase ^ 32) : fbase) + c * 1024;
                    s16x8 vb = *(const s16x8*)(&Vt[u][vidx]);
                    accB[c] = __builtin_amdgcn_mfma_f32_16x16x32_bf16(pa, vb, accB[c], 0, 0, 0);
                }
                sumB = __builtin_amdgcn_mfma_f32_16x16x32_bf16(pa, onesb, sumB, 0, 0, 0);
            }
            __builtin_amdgcn_s_setprio(0);
        }
        mwA = mwA_n;  mwB = mwB_n;
    }

    // epilogue: row sums are lane-local (ones-trick), no shuffles needed
#pragma unroll
    for (int r = 0; r < 4; ++r) {
        const float invA = 1.0f / sumA[r];
        const size_t oA = head_off + (size_t)(qb + quad * 4 + r) * C_;
        O[oA + l16]      = accA[0][r] * invA;
        O[oA + l16 + 16] = accA[1][r] * invA;
        O[oA + l16 + 32] = accA[2][r] * invA;
        O[oA + l16 + 48] = accA[3][r] * invA;
        const float invB = 1.0f / sumB[r];
        const size_t oB = head_off + (size_t)(qb + 16 + quad * 4 + r) * C_;
        O[oB + l16]      = accB[0][r] * invB;
        O[oB + l16 + 16] = accB[1][r] * invB;
        O[oB + l16 + 32] = accB[2][r] * invB;
        O[oB + l16 + 48] = accB[3][r] * invB;
    }
}

// ================== fallback (R6 verbatim): used if ws_size too small =========
#define KSTR 72
#define VSTR 72
__global__ __launch_bounds__(512, 4)
void mha_fwd_fb(const float* __restrict__ Q, const float* __restrict__ K,
                const float* __restrict__ V, const unsigned* __restrict__ bits,
                float* __restrict__ O) {
    __shared__ ushort Kl[2][KT * KSTR];
    __shared__ ushort Vt[2][HD_ * VSTR];
    __shared__ ushort Pl[NW][16 * PSTR];
    const int qt = blockIdx.x, h = blockIdx.y, b = blockIdx.z, tid = threadIdx.x;
    const int w = tid >> 6, lane = tid & 63, l16 = lane & 15, quad = lane >> 4;
    const size_t head_off = (size_t)b * N_ * C_ + (size_t)h * HD_;
    const int qb = qt * QB + w * 16;
    const float qs = 0.125f * 1.44269504088896f;
    const size_t qoff = head_off + (size_t)(qb + l16) * C_ + quad * 8;
    float4 q0 = *(const float4*)(Q + qoff);
    float4 q1 = *(const float4*)(Q + qoff + 4);
    float4 q2 = *(const float4*)(Q + qoff + 32);
    float4 q3 = *(const float4*)(Q + qoff + 36);
    q0.x*=qs; q0.y*=qs; q0.z*=qs; q0.w*=qs;
    q1.x*=qs; q1.y*=qs; q1.z*=qs; q1.w*=qs;
    q2.x*=qs; q2.y*=qs; q2.z*=qs; q2.w*=qs;
    q3.x*=qs; q3.y*=qs; q3.z*=qs; q3.w*=qs;
    const s16x8 qa0 = cvt8(q0, q1);
    const s16x8 qa1 = cvt8(q2, q3);
    f32x4 acc[4];
#pragma unroll
    for (int c = 0; c < 4; ++c) acc[c] = f32x4{0.f, 0.f, 0.f, 0.f};
    float lsum = 0.f;
    const int skey = tid >> 3, sd0 = (tid & 7) * 8;
    const int kp = tid >> 4, vd0 = (tid & 15) * 4;
    const int vcol = 2 * (kp & 3) + ((((kp >> 2) ^ (vd0 >> 3)) & 7) << 3);
    const unsigned* brow = bits + ((size_t)b * N_ + qb + l16) * (N_ / 32);
    const float SHIFT = 16.0f;
    {
        const size_t kbase = head_off + (size_t)skey * C_ + sd0;
        float4 kA = *(const float4*)(K + kbase);
        float4 kB = *(const float4*)(K + kbase + 4);
        *(s16x8*)(&Kl[0][skey * KSTR + sd0]) = cvt8(kA, kB);
        const size_t vbase = head_off + (size_t)(2 * kp) * C_ + vd0;
        float4 vA = *(const float4*)(V + vbase);
        float4 vB = *(const float4*)(V + vbase + C_);
        const float* ap = (const float*)&vA;
        const float* bp = (const float*)&vB;
#pragma unroll
        for (int i = 0; i < 4; ++i) {
            __hip_bfloat162 pr = __float22bfloat162_rn(float2{ap[i], bp[i]});
            *(unsigned*)(&Vt[0][(vd0 + i) * VSTR + vcol]) = *(unsigned*)&pr;
        }
    }
    for (int kt = 0; kt < NT; ++kt) {
        const int cur = kt & 1;
        float4 kA, kB, vA, vB;
        const bool has_next = (kt + 1 < NT);
        if (has_next) {
            const size_t kbase = head_off + (size_t)((kt + 1) * KT + skey) * C_ + sd0;
            kA = *(const float4*)(K + kbase);
            kB = *(const float4*)(K + kbase + 4);
            const size_t vbase = head_off + (size_t)((kt + 1) * KT + 2 * kp) * C_ + vd0;
            vA = *(const float4*)(V + vbase);
            vB = *(const float4*)(V + vbase + C_);
        }
        const unsigned w0 = brow[2 * kt];
        const unsigned w1 = brow[2 * kt + 1];
        __syncthreads();
        f32x4 s[4];
#pragma unroll
        for (int t = 0; t < 4; ++t) {
            s16x8 kb0 = *(const s16x8*)(&Kl[cur][(t * 16 + l16) * KSTR + quad * 8]);
            s16x8 kb1 = *(const s16x8*)(&Kl[cur][(t * 16 + l16) * KSTR + quad * 8 + 32]);
            f32x4 z = {0.f, 0.f, 0.f, 0.f};
            z = __builtin_amdgcn_mfma_f32_16x16x32_bf16(kb0, qa0, z, 0, 0, 0);
            z = __builtin_amdgcn_mfma_f32_16x16x32_bf16(kb1, qa1, z, 0, 0, 0);
            s[t] = z;
        }
        const unsigned a0 = w0 >> (quad * 4);
        const unsigned a1 = w1 >> (quad * 4);
#pragma unroll
        for (int t = 0; t < 4; ++t) {
            const unsigned aw = (t < 2) ? a0 : a1;
            const int sh = (t & 1) * 16;
            float p0 = exp2f((((aw >> (sh + 0)) & 1u) ? s[t][0] : -1e9f) - SHIFT);
            float p1 = exp2f((((aw >> (sh + 1)) & 1u) ? s[t][1] : -1e9f) - SHIFT);
            float p2 = exp2f((((aw >> (sh + 2)) & 1u) ? s[t][2] : -1e9f) - SHIFT);
            float p3 = exp2f((((aw >> (sh + 3)) & 1u) ? s[t][3] : -1e9f) - SHIFT);
            lsum += (p0 + p1) + (p2 + p3);
            union { s16x4 v; __hip_bfloat162 h2[2]; } uu;
            uu.h2[0] = __float22bfloat162_rn(float2{p0, p1});
            uu.h2[1] = __float22bfloat162_rn(float2{p2, p3});
            *(s16x4*)(&Pl[w][l16 * PSTR + t * 16 + quad * 4]) = uu.v;
        }
#pragma unroll
        for (int half = 0; half < 2; ++half) {
            s16x8 pa = *(const s16x8*)(&Pl[w][l16 * PSTR + half * 32 + quad * 8]);
#pragma unroll
            for (int c = 0; c < 4; ++c) {
                const int dr = c * 16 + l16;
                const int blk = (half * 4 + quad) ^ ((dr >> 3) & 7);
                s16x8 vb = *(const s16x8*)(&Vt[cur][dr * VSTR + blk * 8]);
                acc[c] = __builtin_amdgcn_mfma_f32_16x16x32_bf16(pa, vb, acc[c], 0, 0, 0);
            }
        }
        if (has_next) {
            *(s16x8*)(&Kl[1 - cur][skey * KSTR + sd0]) = cvt8(kA, kB);
            const float* ap = (const float*)&vA;
            const float* bp = (const float*)&vB;
#pragma unroll
            for (int i = 0; i < 4; ++i) {
                __hip_bfloat162 pr = __float22bfloat162_rn(float2{ap[i], bp[i]});
                *(unsigned*)(&Vt[1 - cur][(vd0 + i) * VSTR + vcol]) = *(unsigned*)&pr;
            }
        }
    }
    lsum += __shfl_xor(lsum, 16);
    lsum += __shfl_xor(lsum, 32);
#pragma unroll
    for (int r = 0; r < 4; ++r) {
        const float inv = 1.0f / __shfl(lsum, quad * 4 + r);
        const size_t obase = head_off + (size_t)(qb + quad * 4 + r) * C_;
        O[obase + l16]      = acc[0][r] * inv;
        O[obase + l16 + 16] = acc[1][r] * inv;
        O[obase + l16 + 32] = acc[2][r] * inv;
        O[obase + l16 + 48] = acc[3][r] * inv;
    }
}

extern "C" void kernel_launch(void* const* d_in, const int* in_sizes, int n_in,
                              void* d_out, int out_size, void* d_ws, size_t ws_size,
                              hipStream_t stream) {
    const float* q = (const float*)d_in[0];
    const float* k = (const float*)d_in[1];
    const float* v = (const float*)d_in[2];
    const int*   m = (const int*)d_in[3];
    float*       o = (float*)d_out;

    const size_t BITS_BYTES = (size_t)B_ * N_ * N_ / 8;          // 1 MiB
    const size_t KV_BYTES   = (size_t)B_ * H_ * N_ * HD_ * 2;    // 8.39 MB each
    const size_t NEED       = BITS_BYTES + 2 * KV_BYTES;

    unsigned long long* bits = (unsigned long long*)d_ws;

    if (ws_size >= NEED) {
        ushort* kw = (ushort*)((char*)d_ws + BITS_BYTES);
        ushort* vw = (ushort*)((char*)d_ws + BITS_BYTES + KV_BYTES);
        hipLaunchKernelGGL(prepass, dim3(4608), dim3(256), 0, stream,
                           m, k, v, bits, kw, vw);
        hipLaunchKernelGGL(mha_fwd, dim3(1024), dim3(128), 0, stream,
                           q, kw, vw, (const unsigned*)bits, o);
    } else {
        hipLaunchKernelGGL(pack_mask, dim3(2048), dim3(256), 0, stream, m, bits);
        dim3 grid(N_ / QB, H_, B_);
        hipLaunchKernelGGL(mha_fwd_fb, grid, dim3(512), 0, stream,
                           q, k, v, (const unsigned*)bits, o);
    }
}

// Round 4
// 165.713 us; speedup vs baseline: 1.1237x; 1.0488x over previous
//
#include <hip/hip_runtime.h>
#include <hip/hip_bf16.h>

#define B_ 2
#define N_ 2048
#define C_ 1024
#define H_ 16
#define HD_ 64

#define KT 64            // key tile width per flash iteration
#define NT (N_ / KT)     // 32 tiles
#define TILE_E 4096      // elems per staged tile (64x64 bf16 = 8KB)
#define PSTR 72          // P LDS row stride (fallback kernel)
#define NW 8             // waves per block (fallback kernel)
#define QB 128           // q rows per block (fallback kernel)

#define NWM 4            // waves per block (main kernel)
#define QBM 64           // q rows per block (main: 16 per wave)

typedef short s16x8 __attribute__((ext_vector_type(8)));
typedef short s16x4 __attribute__((ext_vector_type(4)));
typedef float f32x4 __attribute__((ext_vector_type(4)));

__device__ __forceinline__ s16x8 cvt8(float4 a, float4 b) {
    union { s16x8 v; __hip_bfloat162 h[4]; } u;
    u.h[0] = __float22bfloat162_rn(float2{a.x, a.y});
    u.h[1] = __float22bfloat162_rn(float2{a.z, a.w});
    u.h[2] = __float22bfloat162_rn(float2{b.x, b.y});
    u.h[3] = __float22bfloat162_rn(float2{b.z, b.w});
    return u.v;
}

// async 16B/lane global -> LDS (DMA, no VGPR round trip)
__device__ __forceinline__ void gll16(const void* g, void* l) {
    __builtin_amdgcn_global_load_lds(
        (const __attribute__((address_space(1))) unsigned*)g,
        (__attribute__((address_space(3))) unsigned*)l, 16, 0, 0);
}

// ---- standalone pack_mask kept for the fallback path only
__global__ __launch_bounds__(256)
void pack_mask(const int* __restrict__ M, unsigned long long* __restrict__ bits) {
    const int gw   = (blockIdx.x * 256 + threadIdx.x) >> 6;
    const int lane = threadIdx.x & 63;
#pragma unroll
    for (int it = 0; it < 16; ++it) {
        const size_t wi = (size_t)gw * 16 + it;
        unsigned long long bal = __ballot(M[wi * 64 + lane] != 0);
        if (lane == 0) bits[wi] = bal;
    }
}

// ---- fused prepass: mask pack (blocks 0..2047), conv_k (2048..4095),
//      conv_v (4096..4607).
__global__ __launch_bounds__(256)
void prepass(const int* __restrict__ M, const float* __restrict__ K,
             const float* __restrict__ V, unsigned long long* __restrict__ bits,
             ushort* __restrict__ Kw, ushort* __restrict__ Vw) {
    const int bid = blockIdx.x;
    const int tid = threadIdx.x;
    if (bid < 2048) {
        // vectorized mask pack: 16 ints/thread (4x int4 = 64B), 1 ushort out.
        const int gt = bid * 256 + tid;            // 0..524287
        const int4* src = (const int4*)M + (size_t)gt * 4;
        unsigned r = 0;
#pragma unroll
        for (int c = 0; c < 4; ++c) {
            const int4 m4 = src[c];
            r |= (m4.x != 0 ? 1u : 0u) << (c * 4 + 0);
            r |= (m4.y != 0 ? 1u : 0u) << (c * 4 + 1);
            r |= (m4.z != 0 ? 1u : 0u) << (c * 4 + 2);
            r |= (m4.w != 0 ? 1u : 0u) << (c * 4 + 3);
        }
        ((ushort*)bits)[gt] = (ushort)r;
    } else if (bid < 4096) {
        // K fp32 -> bf16, tile-major, KEY-PERMUTED rows (aligns QK^T output
        // layout with the PV A-fragment layout so P stays in registers),
        // d-block XOR swizzle baked in.
        // perm: tile row p for key k: p5=k5, p4=k2, p3p2=k4k3, p1p0=k1k0
        const int gt = (bid - 2048) * 256 + tid;
        const int b  = gt >> 18;
        const int h  = (gt >> 14) & 15;
        const int n  = (gt >> 3) & 2047;
        const int db = gt & 7;
        const size_t src = (size_t)(b * N_ + n) * C_ + h * 64 + db * 8;
        float4 f0 = *(const float4*)(K + src);
        float4 f1 = *(const float4*)(K + src + 4);
        const int key = n & 63, kt = n >> 6;
        const int p = (key & 32) | ((key & 4) << 2) | ((key >> 1) & 12) | (key & 3);
        ushort* dst = Kw + (size_t)((b * H_ + h) * NT + kt) * TILE_E
                         + p * 64 + ((db ^ (p & 7)) * 8);
        *(s16x8*)dst = cvt8(f0, f1);
    } else {
        // V fp32 -> bf16 TRANSPOSED, tile-major, TRUE key order,
        // key-block XOR swizzle.
        const int gt  = (bid - 4096) * 256 + tid;
        const int b   = gt >> 16;
        const int h   = (gt >> 12) & 15;
        const int kt  = (gt >> 7) & 31;
        const int kb4 = (gt >> 3) & 15;
        const int db  = gt & 7;
        const int key0 = kb4 * 4;
        float f[4][8];
#pragma unroll
        for (int i = 0; i < 4; ++i) {
            const size_t src = (size_t)(b * N_ + kt * 64 + key0 + i) * C_ + h * 64 + db * 8;
            *(float4*)&f[i][0] = *(const float4*)(V + src);
            *(float4*)&f[i][4] = *(const float4*)(V + src + 4);
        }
        ushort* tb = Vw + (size_t)((b * H_ + h) * NT + kt) * TILE_E;
#pragma unroll
        for (int j = 0; j < 8; ++j) {
            const int d = db * 8 + j;
            union { s16x4 v; __hip_bfloat162 h2[2]; } u;
            u.h2[0] = __float22bfloat162_rn(float2{f[0][j], f[1][j]});
            u.h2[1] = __float22bfloat162_rn(float2{f[2][j], f[3][j]});
            *(s16x4*)(tb + d * 64 + (((key0 >> 3) ^ (d & 7)) * 8) + (key0 & 7)) = u.v;
        }
    }
}

// ---- main: 256-thread blocks, 16 q/wave, in-register P (no P LDS),
//      LDS = 32768 B, row-sum via MFMA ones-trick, XCD-swizzled grid.
__global__ __launch_bounds__(256, 4)
void mha_fwd(const float* __restrict__ Q, const ushort* __restrict__ Kw,
             const ushort* __restrict__ Vw, const unsigned* __restrict__ bits,
             float* __restrict__ O) {
    __shared__ ushort Kl[2][TILE_E];       // 16 KB
    __shared__ ushort Vt[2][TILE_E];       // 16 KB  -> 32768 B total

    // XCD-aware bijective decode: xcd = sid&7 owns heads 4*xcd..4*xcd+3
    const int sid = blockIdx.x;
    const int jj  = sid >> 3;
    const int hb  = ((sid & 7) << 2) | (jj & 3);   // 0..31 = b*16+h
    const int qt  = jj >> 2;                        // 0..31
    const int h   = hb & 15;
    const int b   = hb >> 4;

    const int tid  = threadIdx.x;
    const int w    = tid >> 6;
    const int lane = tid & 63;
    const int l16  = lane & 15;
    const int quad = lane >> 4;

    const size_t head_off = (size_t)b * N_ * C_ + (size_t)h * HD_;
    const int qb = qt * QBM + w * 16;

    // Q fragment (B-operand of S^T = K Q^T); fold 1/8*log2(e): log2-domain
    const float qs = 0.125f * 1.44269504088896f;
    const size_t qoff = head_off + (size_t)(qb + l16) * C_ + quad * 8;
    float4 q0 = *(const float4*)(Q + qoff);
    float4 q1 = *(const float4*)(Q + qoff + 4);
    float4 q2 = *(const float4*)(Q + qoff + 32);
    float4 q3 = *(const float4*)(Q + qoff + 36);
    q0.x*=qs; q0.y*=qs; q0.z*=qs; q0.w*=qs;
    q1.x*=qs; q1.y*=qs; q1.z*=qs; q1.w*=qs;
    q2.x*=qs; q2.y*=qs; q2.z*=qs; q2.w*=qs;
    q3.x*=qs; q3.y*=qs; q3.z*=qs; q3.w*=qs;
    const s16x8 qa0 = cvt8(q0, q1);
    const s16x8 qa1 = cvt8(q2, q3);

    // constant all-ones bf16 B-fragment: row-sum via MFMA (ones-trick)
    s16x8 onesb;
#pragma unroll
    for (int i = 0; i < 8; ++i) onesb[i] = (short)0x3F80;

    f32x4 acc[4];
#pragma unroll
    for (int c = 0; c < 4; ++c) acc[c] = f32x4{0.f, 0.f, 0.f, 0.f};
    f32x4 sum = f32x4{0.f, 0.f, 0.f, 0.f};

    // hoisted fragment element base (loop-invariant)
    const int fbase = l16 * 64 + ((quad ^ (l16 & 7)) * 8);

    // staging pointers: lane covers bytes tid*16 of each 8KB tile (2 rounds)
    const size_t tilebase = (size_t)((b * H_ + h) * NT) * TILE_E;
    const ushort* Kg = Kw + tilebase + (size_t)tid * 8;
    const ushort* Vg = Vw + tilebase + (size_t)tid * 8;

    const unsigned* mq = bits + ((size_t)b * N_ + qb + l16) * (N_ / 32);

    // issue tile 0 into buffer 0 (drained by first barrier)
    gll16(Kg,        &Kl[0][w * 512]);
    gll16(Kg + 2048, &Kl[0][w * 512 + 2048]);
    gll16(Vg,        &Vt[0][w * 512]);
    gll16(Vg + 2048, &Vt[0][w * 512 + 2048]);
    const ushort* Kg_pf = Kg + TILE_E;
    const ushort* Vg_pf = Vg + TILE_E;

    uint4 mw = *(const uint4*)mq;  mq += 4;   // mask words for first tile pair

    for (int kt2 = 0; kt2 < NT; kt2 += 2) {
        // prefetch next pair's mask words (final over-read lands in Kw region)
        const uint4 mw_nxt = *(const uint4*)mq;  mq += 4;
        const bool pf1 = (kt2 + 2 < NT);
#pragma unroll
        for (int u = 0; u < 2; ++u) {        // u == buffer index (compile-time)
            __syncthreads();   // tile staged; all waves done reading other buf
            if (u == 0 || pf1) {             // prefetch next tile into other buf
                gll16(Kg_pf,        &Kl[1 - u][w * 512]);
                gll16(Kg_pf + 2048, &Kl[1 - u][w * 512 + 2048]);
                gll16(Vg_pf,        &Vt[1 - u][w * 512]);
                gll16(Vg_pf + 2048, &Vt[1 - u][w * 512 + 2048]);
                Kg_pf += TILE_E;  Vg_pf += TILE_E;
            }
            const unsigned w0 = u ? mw.z : mw.x;
            const unsigned w1 = u ? mw.w : mw.y;

            // S^T = K Q^T on the PERMUTED key rows: position (t,quad,r) holds
            // key 32*(t>>1) + 8*quad + 4*(t&1) + r  == PV A-fragment order.
            f32x4 s[4];
            __builtin_amdgcn_s_setprio(1);
#pragma unroll
            for (int t = 0; t < 4; ++t) {
                s16x8 kb0 = *(const s16x8*)(&Kl[u][fbase + t * 1024]);
                s16x8 kb1 = *(const s16x8*)(&Kl[u][(fbase ^ 32) + t * 1024]);
                f32x4 z = {0.f, 0.f, 0.f, 0.f};
                z = __builtin_amdgcn_mfma_f32_16x16x32_bf16(kb0, qa0, z, 0, 0, 0);
                z = __builtin_amdgcn_mfma_f32_16x16x32_bf16(kb1, qa1, z, 0, 0, 0);
                s[t] = z;
            }
            __builtin_amdgcn_s_setprio(0);

            // softmax (unnormalized p = exp2(s)); mask bit for (t,quad,r) is
            // key = 32*(t>>1) + 8*quad + 4*(t&1) + r of the 64-bit tile mask.
            const unsigned aw0 = w0 >> (quad * 8);   // t=0 (lo nibble) / t=1 (hi)
            const unsigned aw1 = w1 >> (quad * 8);   // t=2 / t=3
            union { s16x8 v; __hip_bfloat162 h2[4]; } pk0, pk1;
#pragma unroll
            for (int t = 0; t < 4; ++t) {
                const unsigned aw = ((t < 2) ? aw0 : aw1) >> ((t & 1) * 4);
                float p0 = __builtin_amdgcn_exp2f(((aw >> 0) & 1u) ? s[t][0] : -1e9f);
                float p1 = __builtin_amdgcn_exp2f(((aw >> 1) & 1u) ? s[t][1] : -1e9f);
                float p2 = __builtin_amdgcn_exp2f(((aw >> 2) & 1u) ? s[t][2] : -1e9f);
                float p3 = __builtin_amdgcn_exp2f(((aw >> 3) & 1u) ? s[t][3] : -1e9f);
                __hip_bfloat162 lo = __float22bfloat162_rn(float2{p0, p1});
                __hip_bfloat162 hi = __float22bfloat162_rn(float2{p2, p3});
                if      (t == 0) { pk0.h2[0] = lo; pk0.h2[1] = hi; }
                else if (t == 1) { pk0.h2[2] = lo; pk0.h2[3] = hi; }
                else if (t == 2) { pk1.h2[0] = lo; pk1.h2[1] = hi; }
                else             { pk1.h2[2] = lo; pk1.h2[3] = hi; }
            }

            // PV + ones-sum: P is already the A-fragment, fully in-register.
            __builtin_amdgcn_s_setprio(1);
#pragma unroll
            for (int half = 0; half < 2; ++half) {
                const s16x8 pa = half ? pk1.v : pk0.v;
#pragma unroll
                for (int c = 0; c < 4; ++c) {
                    const int vidx = (half ? (fbase ^ 32) : fbase) + c * 1024;
                    s16x8 vb = *(const s16x8*)(&Vt[u][vidx]);
                    acc[c] = __builtin_amdgcn_mfma_f32_16x16x32_bf16(pa, vb, acc[c], 0, 0, 0);
                }
                sum = __builtin_amdgcn_mfma_f32_16x16x32_bf16(pa, onesb, sum, 0, 0, 0);
            }
            __builtin_amdgcn_s_setprio(0);
        }
        mw = mw_nxt;
    }

    // epilogue: row sums are lane-local (ones-trick), no shuffles needed
#pragma unroll
    for (int r = 0; r < 4; ++r) {
        const float inv = 1.0f / sum[r];
        const size_t obase = head_off + (size_t)(qb + quad * 4 + r) * C_;
        O[obase + l16]      = acc[0][r] * inv;
        O[obase + l16 + 16] = acc[1][r] * inv;
        O[obase + l16 + 32] = acc[2][r] * inv;
        O[obase + l16 + 48] = acc[3][r] * inv;
    }
}

// ================== fallback (R6 verbatim): used if ws_size too small =========
#define KSTR 72
#define VSTR 72
__global__ __launch_bounds__(512, 4)
void mha_fwd_fb(const float* __restrict__ Q, const float* __restrict__ K,
                const float* __restrict__ V, const unsigned* __restrict__ bits,
                float* __restrict__ O) {
    __shared__ ushort Kl[2][KT * KSTR];
    __shared__ ushort Vt[2][HD_ * VSTR];
    __shared__ ushort Pl[NW][16 * PSTR];
    const int qt = blockIdx.x, h = blockIdx.y, b = blockIdx.z, tid = threadIdx.x;
    const int w = tid >> 6, lane = tid & 63, l16 = lane & 15, quad = lane >> 4;
    const size_t head_off = (size_t)b * N_ * C_ + (size_t)h * HD_;
    const int qb = qt * QB + w * 16;
    const float qs = 0.125f * 1.44269504088896f;
    const size_t qoff = head_off + (size_t)(qb + l16) * C_ + quad * 8;
    float4 q0 = *(const float4*)(Q + qoff);
    float4 q1 = *(const float4*)(Q + qoff + 4);
    float4 q2 = *(const float4*)(Q + qoff + 32);
    float4 q3 = *(const float4*)(Q + qoff + 36);
    q0.x*=qs; q0.y*=qs; q0.z*=qs; q0.w*=qs;
    q1.x*=qs; q1.y*=qs; q1.z*=qs; q1.w*=qs;
    q2.x*=qs; q2.y*=qs; q2.z*=qs; q2.w*=qs;
    q3.x*=qs; q3.y*=qs; q3.z*=qs; q3.w*=qs;
    const s16x8 qa0 = cvt8(q0, q1);
    const s16x8 qa1 = cvt8(q2, q3);
    f32x4 acc[4];
#pragma unroll
    for (int c = 0; c < 4; ++c) acc[c] = f32x4{0.f, 0.f, 0.f, 0.f};
    float lsum = 0.f;
    const int skey = tid >> 3, sd0 = (tid & 7) * 8;
    const int kp = tid >> 4, vd0 = (tid & 15) * 4;
    const int vcol = 2 * (kp & 3) + ((((kp >> 2) ^ (vd0 >> 3)) & 7) << 3);
    const unsigned* brow = bits + ((size_t)b * N_ + qb + l16) * (N_ / 32);
    const float SHIFT = 16.0f;
    {
        const size_t kbase = head_off + (size_t)skey * C_ + sd0;
        float4 kA = *(const float4*)(K + kbase);
        float4 kB = *(const float4*)(K + kbase + 4);
        *(s16x8*)(&Kl[0][skey * KSTR + sd0]) = cvt8(kA, kB);
        const size_t vbase = head_off + (size_t)(2 * kp) * C_ + vd0;
        float4 vA = *(const float4*)(V + vbase);
        float4 vB = *(const float4*)(V + vbase + C_);
        const float* ap = (const float*)&vA;
        const float* bp = (const float*)&vB;
#pragma unroll
        for (int i = 0; i < 4; ++i) {
            __hip_bfloat162 pr = __float22bfloat162_rn(float2{ap[i], bp[i]});
            *(unsigned*)(&Vt[0][(vd0 + i) * VSTR + vcol]) = *(unsigned*)&pr;
        }
    }
    for (int kt = 0; kt < NT; ++kt) {
        const int cur = kt & 1;
        float4 kA, kB, vA, vB;
        const bool has_next = (kt + 1 < NT);
        if (has_next) {
            const size_t kbase = head_off + (size_t)((kt + 1) * KT + skey) * C_ + sd0;
            kA = *(const float4*)(K + kbase);
            kB = *(const float4*)(K + kbase + 4);
            const size_t vbase = head_off + (size_t)((kt + 1) * KT + 2 * kp) * C_ + vd0;
            vA = *(const float4*)(V + vbase);
            vB = *(const float4*)(V + vbase + C_);
        }
        const unsigned w0 = brow[2 * kt];
        const unsigned w1 = brow[2 * kt + 1];
        __syncthreads();
        f32x4 s[4];
#pragma unroll
        for (int t = 0; t < 4; ++t) {
            s16x8 kb0 = *(const s16x8*)(&Kl[cur][(t * 16 + l16) * KSTR + quad * 8]);
            s16x8 kb1 = *(const s16x8*)(&Kl[cur][(t * 16 + l16) * KSTR + quad * 8 + 32]);
            f32x4 z = {0.f, 0.f, 0.f, 0.f};
            z = __builtin_amdgcn_mfma_f32_16x16x32_bf16(kb0, qa0, z, 0, 0, 0);
            z = __builtin_amdgcn_mfma_f32_16x16x32_bf16(kb1, qa1, z, 0, 0, 0);
            s[t] = z;
        }
        const unsigned a0 = w0 >> (quad * 4);
        const unsigned a1 = w1 >> (quad * 4);
#pragma unroll
        for (int t = 0; t < 4; ++t) {
            const unsigned aw = (t < 2) ? a0 : a1;
            const int sh = (t & 1) * 16;
            float p0 = exp2f((((aw >> (sh + 0)) & 1u) ? s[t][0] : -1e9f) - SHIFT);
            float p1 = exp2f((((aw >> (sh + 1)) & 1u) ? s[t][1] : -1e9f) - SHIFT);
            float p2 = exp2f((((aw >> (sh + 2)) & 1u) ? s[t][2] : -1e9f) - SHIFT);
            float p3 = exp2f((((aw >> (sh + 3)) & 1u) ? s[t][3] : -1e9f) - SHIFT);
            lsum += (p0 + p1) + (p2 + p3);
            union { s16x4 v; __hip_bfloat162 h2[2]; } uu;
            uu.h2[0] = __float22bfloat162_rn(float2{p0, p1});
            uu.h2[1] = __float22bfloat162_rn(float2{p2, p3});
            *(s16x4*)(&Pl[w][l16 * PSTR + t * 16 + quad * 4]) = uu.v;
        }
#pragma unroll
        for (int half = 0; half < 2; ++half) {
            s16x8 pa = *(const s16x8*)(&Pl[w][l16 * PSTR + half * 32 + quad * 8]);
#pragma unroll
            for (int c = 0; c < 4; ++c) {
                const int dr = c * 16 + l16;
                const int blk = (half * 4 + quad) ^ ((dr >> 3) & 7);
                s16x8 vb = *(const s16x8*)(&Vt[cur][dr * VSTR + blk * 8]);
                acc[c] = __builtin_amdgcn_mfma_f32_16x16x32_bf16(pa, vb, acc[c], 0, 0, 0);
            }
        }
        if (has_next) {
            *(s16x8*)(&Kl[1 - cur][skey * KSTR + sd0]) = cvt8(kA, kB);
            const float* ap = (const float*)&vA;
            const float* bp = (const float*)&vB;
#pragma unroll
            for (int i = 0; i < 4; ++i) {
                __hip_bfloat162 pr = __float22bfloat162_rn(float2{ap[i], bp[i]});
                *(unsigned*)(&Vt[1 - cur][(vd0 + i) * VSTR + vcol]) = *(unsigned*)&pr;
            }
        }
    }
    lsum += __shfl_xor(lsum, 16);
    lsum += __shfl_xor(lsum, 32);
#pragma unroll
    for (int r = 0; r < 4; ++r) {
        const float inv = 1.0f / __shfl(lsum, quad * 4 + r);
        const size_t obase = head_off + (size_t)(qb + quad * 4 + r) * C_;
        O[obase + l16]      = acc[0][r] * inv;
        O[obase + l16 + 16] = acc[1][r] * inv;
        O[obase + l16 + 32] = acc[2][r] * inv;
        O[obase + l16 + 48] = acc[3][r] * inv;
    }
}

extern "C" void kernel_launch(void* const* d_in, const int* in_sizes, int n_in,
                              void* d_out, int out_size, void* d_ws, size_t ws_size,
                              hipStream_t stream) {
    const float* q = (const float*)d_in[0];
    const float* k = (const float*)d_in[1];
    const float* v = (const float*)d_in[2];
    const int*   m = (const int*)d_in[3];
    float*       o = (float*)d_out;

    const size_t BITS_BYTES = (size_t)B_ * N_ * N_ / 8;          // 1 MiB
    const size_t KV_BYTES   = (size_t)B_ * H_ * N_ * HD_ * 2;    // 8.39 MB each
    const size_t NEED       = BITS_BYTES + 2 * KV_BYTES;

    unsigned long long* bits = (unsigned long long*)d_ws;

    if (ws_size >= NEED) {
        ushort* kw = (ushort*)((char*)d_ws + BITS_BYTES);
        ushort* vw = (ushort*)((char*)d_ws + BITS_BYTES + KV_BYTES);
        hipLaunchKernelGGL(prepass, dim3(4608), dim3(256), 0, stream,
                           m, k, v, bits, kw, vw);
        hipLaunchKernelGGL(mha_fwd, dim3(1024), dim3(256), 0, stream,
                           q, kw, vw, (const unsigned*)bits, o);
    } else {
        hipLaunchKernelGGL(pack_mask, dim3(2048), dim3(256), 0, stream, m, bits);
        dim3 grid(N_ / QB, H_, B_);
        hipLaunchKernelGGL(mha_fwd_fb, grid, dim3(512), 0, stream,
                           q, k, v, (const unsigned*)bits, o);
    }
}